// Round 10
// baseline (97.707 us; speedup 1.0000x reference)
//
#include <hip/hip_runtime.h>
#include <math.h>

#define H 1024
#define B 64
#define L 2048

#define GC 16   // g-chunks (64 g each) — summed in the scores prologue
#define HC 4    // h-chunks (256 h each)
#define BG 16   // b-groups (4 b per thread)

typedef float f32x4 __attribute__((ext_vector_type(4)));

// ---------------------------------------------------------------------------
// Kernel 1: partial[b][gc][h] = sum_{g in chunk gc} hidden[b,g] * W[g,h]
// grid (GC, HC, BG) = 1024 blocks (4/CU). Thread owns one h, 4 b's in regs.
// 64 g-iters, unroll 8 -> 8 latency stall-groups. hidden reads wave-uniform
// -> scalar loads. partial = 4 MB, L2-resident for the scores prologue.
// ---------------------------------------------------------------------------
__global__ __launch_bounds__(256) void u_partial_kernel(
        const float* __restrict__ hidden,
        const float* __restrict__ W,
        float* __restrict__ partial) {
    const int h  = blockIdx.y * 256 + threadIdx.x;
    const int g0 = blockIdx.x * 64;
    const int b0 = blockIdx.z * 4;

    float acc[4];
#pragma unroll
    for (int bb = 0; bb < 4; ++bb) acc[bb] = 0.f;

#pragma unroll 8
    for (int gg = 0; gg < 64; ++gg) {
        const int g = g0 + gg;
        const float w = W[(size_t)g * H + h];
#pragma unroll
        for (int bb = 0; bb < 4; ++bb) {
            acc[bb] = fmaf(hidden[(b0 + bb) * H + g], w, acc[bb]);
        }
    }

#pragma unroll
    for (int bb = 0; bb < 4; ++bb) {
        partial[((size_t)(b0 + bb) * GC + blockIdx.x) * H + h] = acc[bb];
    }
}

// ---------------------------------------------------------------------------
// Kernel 2: scores[b,l] = dot(enc[l,b,:], u[b,:]) with u materialized in the
// prologue: u-fragment (16 VGPRs) = sum over GC=16 L2-hot partial chunks.
// Stream phase: ITER=32 l's per wave for fixed b, nt enc loads (zero reuse),
// unroll 4 -> 16 x 1 KB wave-loads in flight, wave-private LDS-transpose
// reduction (no block barrier), one coalesced 128 B store per wave.
// ---------------------------------------------------------------------------
#define ITER 32
__global__ __launch_bounds__(256, 4) void scores_kernel(
        const f32x4* __restrict__ enc4,
        const f32x4* __restrict__ partial4,
        float* __restrict__ scores) {
    __shared__ float red[4][64][33];
    const int wave = threadIdx.x >> 6;
    const int lane = threadIdx.x & 63;
    const int gw   = blockIdx.x * 4 + wave;        // [0, B*L/ITER)
    const int b    = gw & (B - 1);
    const int l0   = (gw >> 6) * ITER;

    // ---- prologue: u[b, lane-slice] = sum_gc partial[b][gc][slice] ----
    const f32x4* __restrict__ pb = partial4 + (size_t)b * GC * (H / 4);
    f32x4 uv0 = pb[lane];
    f32x4 uv1 = pb[64 + lane];
    f32x4 uv2 = pb[128 + lane];
    f32x4 uv3 = pb[192 + lane];
#pragma unroll
    for (int gc = 1; gc < GC; ++gc) {
        const f32x4* __restrict__ pc = pb + (size_t)gc * (H / 4);
        uv0 += pc[lane];
        uv1 += pc[64 + lane];
        uv2 += pc[128 + lane];
        uv3 += pc[192 + lane];
    }

    const f32x4* __restrict__ e = enc4 + ((size_t)l0 * B + b) * (H / 4);

    float acc[ITER];
#pragma unroll 4
    for (int i = 0; i < ITER; ++i) {
        const f32x4* __restrict__ ei = e + (size_t)i * B * (H / 4);
        const f32x4 e0 = __builtin_nontemporal_load(ei + lane);
        const f32x4 e1 = __builtin_nontemporal_load(ei + 64 + lane);
        const f32x4 e2 = __builtin_nontemporal_load(ei + 128 + lane);
        const f32x4 e3 = __builtin_nontemporal_load(ei + 192 + lane);
        float a = e0.x * uv0.x;
        a = fmaf(e0.y, uv0.y, a);
        a = fmaf(e0.z, uv0.z, a);
        a = fmaf(e0.w, uv0.w, a);
        a = fmaf(e1.x, uv1.x, a);
        a = fmaf(e1.y, uv1.y, a);
        a = fmaf(e1.z, uv1.z, a);
        a = fmaf(e1.w, uv1.w, a);
        a = fmaf(e2.x, uv2.x, a);
        a = fmaf(e2.y, uv2.y, a);
        a = fmaf(e2.z, uv2.z, a);
        a = fmaf(e2.w, uv2.w, a);
        a = fmaf(e3.x, uv3.x, a);
        a = fmaf(e3.y, uv3.y, a);
        a = fmaf(e3.z, uv3.z, a);
        a = fmaf(e3.w, uv3.w, a);
        acc[i] = a;
    }

    // ---- LDS-transpose reduction (wave-private tile, no block barrier) ----
#pragma unroll
    for (int q = 0; q < ITER; ++q) red[wave][lane][q] = acc[q];
    asm volatile("" ::: "memory");   // compile-time order; HW: per-wave DS FIFO

    const int a    = lane & 31;
    const int base = (lane >> 5) * 32;
    float s = 0.f;
#pragma unroll
    for (int r = 0; r < 32; ++r) s += red[wave][base + r][a];
    s += __shfl_xor(s, 32);

    if (lane < 32) {
        scores[(size_t)b * L + l0 + lane] = s;
    }
}

// ---------------------------------------------------------------------------
// Kernel 3: in-place row softmax, one block (1024 threads) per b, 2 floats
// per thread (float2). Wave shuffle reduce + LDS combine across 16 waves.
// ---------------------------------------------------------------------------
__global__ __launch_bounds__(1024) void softmax_kernel(float* __restrict__ out) {
    __shared__ float redm[16];
    __shared__ float reds[16];
    const int b    = blockIdx.x;
    const int tid  = threadIdx.x;
    const int wave = tid >> 6;
    const int lane = tid & 63;

    float2* __restrict__ r2 = (float2*)(out + (size_t)b * L);
    float2 a = r2[tid];

    float m = fmaxf(a.x, a.y);
#pragma unroll
    for (int off = 32; off; off >>= 1) m = fmaxf(m, __shfl_down(m, off));
    if (lane == 0) redm[wave] = m;
    __syncthreads();
    if (wave == 0) {
        float mm = redm[lane & 15];
#pragma unroll
        for (int off = 8; off; off >>= 1) mm = fmaxf(mm, __shfl_down(mm, off));
        if (lane == 0) redm[0] = mm;
    }
    __syncthreads();
    m = redm[0];

    const float e0 = expf(a.x - m);
    const float e1 = expf(a.y - m);

    float s = e0 + e1;
#pragma unroll
    for (int off = 32; off; off >>= 1) s += __shfl_down(s, off);
    if (lane == 0) reds[wave] = s;
    __syncthreads();
    if (wave == 0) {
        float ss = reds[lane & 15];
#pragma unroll
        for (int off = 8; off; off >>= 1) ss += __shfl_down(ss, off);
        if (lane == 0) reds[0] = ss;
    }
    __syncthreads();
    s = reds[0];

    const float inv = 1.f / s;
    a.x = e0 * inv;
    a.y = e1 * inv;
    r2[tid] = a;
}

extern "C" void kernel_launch(void* const* d_in, const int* in_sizes, int n_in,
                              void* d_out, int out_size, void* d_ws, size_t ws_size,
                              hipStream_t stream) {
    const float* hidden = (const float*)d_in[0];  // [B, H]
    const float* enc    = (const float*)d_in[1];  // [L, B, H]
    const float* W      = (const float*)d_in[2];  // [H, H]
    // d_in[3] (bias) cancels in the softmax over l — provably irrelevant.

    float* partial = (float*)d_ws;                        // [B, GC, H]  4 MB
    float* out     = (float*)d_out;                       // [B, 1, L]   fp32

    // 1) partial = split-K hidden @ W (GC=16 chunks; summed in scores prologue)
    u_partial_kernel<<<dim3(GC, HC, BG), 256, 0, stream>>>(hidden, W, partial);

    // 2) scores[b,l] = dot(enc[l,b,:], sum_gc partial[b][gc][:]) -> d_out
    scores_kernel<<<(B * L / ITER) / 4, 256, 0, stream>>>(
        (const f32x4*)enc, (const f32x4*)partial, out);

    // 3) softmax over l, in place
    softmax_kernel<<<B, 1024, 0, stream>>>(out);
}

// Round 11
// 96.170 us; speedup vs baseline: 1.0160x; 1.0160x over previous
//
#include <hip/hip_runtime.h>
#include <math.h>

#define H 1024
#define B 64
#define L 2048

#define GC 8    // g-chunks (128 g each) — summed in the scores prologue
#define HC 4    // h-chunks (256 h each)
#define BG 16   // b-groups (4 b per thread)

typedef float f32x4 __attribute__((ext_vector_type(4)));

// ---------------------------------------------------------------------------
// Kernel 1: partial[b][gc][h] = sum_{g in chunk gc} hidden[b,g] * W[g,h]
// grid (GC, HC, BG) = 512 blocks (2/CU). Thread owns one h, 4 b's in regs.
// 128 g-iters, unroll 8 -> 16 stall groups, hidden via wave-uniform scalar
// loads. partial is only 2 MB -> stays L2-resident for the scores prologue.
// NO u_reduce kernel: the scores kernel sums the GC=8 chunks itself.
// ---------------------------------------------------------------------------
__global__ __launch_bounds__(256) void u_partial_kernel(
        const float* __restrict__ hidden,
        const float* __restrict__ W,
        float* __restrict__ partial) {
    const int h  = blockIdx.y * 256 + threadIdx.x;
    const int g0 = blockIdx.x * 128;
    const int b0 = blockIdx.z * 4;

    float acc[4];
#pragma unroll
    for (int bb = 0; bb < 4; ++bb) acc[bb] = 0.f;

#pragma unroll 8
    for (int gg = 0; gg < 128; ++gg) {
        const int g = g0 + gg;
        const float w = W[(size_t)g * H + h];
#pragma unroll
        for (int bb = 0; bb < 4; ++bb) {
            acc[bb] = fmaf(hidden[(b0 + bb) * H + g], w, acc[bb]);
        }
    }

#pragma unroll
    for (int bb = 0; bb < 4; ++bb) {
        partial[((size_t)(b0 + bb) * GC + blockIdx.x) * H + h] = acc[bb];
    }
}

// ---------------------------------------------------------------------------
// Kernel 2: scores[b,l] = dot(enc[l,b,:], u[b,:]) with u materialized in the
// prologue: u-fragment (16 VGPRs) = sum over GC=8 L2-hot partial chunks.
// Stream phase: ITER=32 l's per wave for fixed b, nt enc loads (zero reuse),
// unroll 4 -> 16 x 1 KB wave-loads in flight, wave-private LDS-transpose
// reduction (no block barrier), one coalesced 128 B store per wave.
// ---------------------------------------------------------------------------
#define ITER 32
__global__ __launch_bounds__(256, 4) void scores_kernel(
        const f32x4* __restrict__ enc4,
        const f32x4* __restrict__ partial4,
        float* __restrict__ scores) {
    __shared__ float red[4][64][33];
    const int wave = threadIdx.x >> 6;
    const int lane = threadIdx.x & 63;
    const int gw   = blockIdx.x * 4 + wave;        // [0, B*L/ITER)
    const int b    = gw & (B - 1);
    const int l0   = (gw >> 6) * ITER;

    // ---- prologue: u[b, lane-slice] = sum_gc partial[b][gc][slice] ----
    const f32x4* __restrict__ pb = partial4 + (size_t)b * GC * (H / 4);
    f32x4 uv0 = pb[lane];
    f32x4 uv1 = pb[64 + lane];
    f32x4 uv2 = pb[128 + lane];
    f32x4 uv3 = pb[192 + lane];
#pragma unroll
    for (int gc = 1; gc < GC; ++gc) {
        const f32x4* __restrict__ pc = pb + (size_t)gc * (H / 4);
        uv0 += pc[lane];
        uv1 += pc[64 + lane];
        uv2 += pc[128 + lane];
        uv3 += pc[192 + lane];
    }

    const f32x4* __restrict__ e = enc4 + ((size_t)l0 * B + b) * (H / 4);

    float acc[ITER];
#pragma unroll 4
    for (int i = 0; i < ITER; ++i) {
        const f32x4* __restrict__ ei = e + (size_t)i * B * (H / 4);
        const f32x4 e0 = __builtin_nontemporal_load(ei + lane);
        const f32x4 e1 = __builtin_nontemporal_load(ei + 64 + lane);
        const f32x4 e2 = __builtin_nontemporal_load(ei + 128 + lane);
        const f32x4 e3 = __builtin_nontemporal_load(ei + 192 + lane);
        float a = e0.x * uv0.x;
        a = fmaf(e0.y, uv0.y, a);
        a = fmaf(e0.z, uv0.z, a);
        a = fmaf(e0.w, uv0.w, a);
        a = fmaf(e1.x, uv1.x, a);
        a = fmaf(e1.y, uv1.y, a);
        a = fmaf(e1.z, uv1.z, a);
        a = fmaf(e1.w, uv1.w, a);
        a = fmaf(e2.x, uv2.x, a);
        a = fmaf(e2.y, uv2.y, a);
        a = fmaf(e2.z, uv2.z, a);
        a = fmaf(e2.w, uv2.w, a);
        a = fmaf(e3.x, uv3.x, a);
        a = fmaf(e3.y, uv3.y, a);
        a = fmaf(e3.z, uv3.z, a);
        a = fmaf(e3.w, uv3.w, a);
        acc[i] = a;
    }

    // ---- LDS-transpose reduction (wave-private tile, no block barrier) ----
#pragma unroll
    for (int q = 0; q < ITER; ++q) red[wave][lane][q] = acc[q];
    asm volatile("" ::: "memory");   // compile-time order; HW: per-wave DS FIFO

    const int a    = lane & 31;
    const int base = (lane >> 5) * 32;
    float s = 0.f;
#pragma unroll
    for (int r = 0; r < 32; ++r) s += red[wave][base + r][a];
    s += __shfl_xor(s, 32);

    if (lane < 32) {
        scores[(size_t)b * L + l0 + lane] = s;
    }
}

// ---------------------------------------------------------------------------
// Kernel 3: in-place row softmax, one block (512 threads) per b, 1 float4/thr.
// ---------------------------------------------------------------------------
__global__ __launch_bounds__(512) void softmax_kernel(float* __restrict__ out) {
    __shared__ float redm[8];
    __shared__ float reds[8];
    const int b    = blockIdx.x;
    const int tid  = threadIdx.x;
    const int wave = tid >> 6;
    const int lane = tid & 63;

    float4* __restrict__ r4 = (float4*)(out + (size_t)b * L);
    float4 a = r4[tid];

    float m = fmaxf(fmaxf(a.x, a.y), fmaxf(a.z, a.w));
#pragma unroll
    for (int off = 32; off; off >>= 1) m = fmaxf(m, __shfl_down(m, off));
    if (lane == 0) redm[wave] = m;
    __syncthreads();
    m = fmaxf(fmaxf(fmaxf(redm[0], redm[1]), fmaxf(redm[2], redm[3])),
              fmaxf(fmaxf(redm[4], redm[5]), fmaxf(redm[6], redm[7])));

    float e0 = expf(a.x - m), e1 = expf(a.y - m);
    float e2 = expf(a.z - m), e3 = expf(a.w - m);

    float s = (e0 + e1) + (e2 + e3);
#pragma unroll
    for (int off = 32; off; off >>= 1) s += __shfl_down(s, off);
    if (lane == 0) reds[wave] = s;
    __syncthreads();
    s = ((reds[0] + reds[1]) + (reds[2] + reds[3])) +
        ((reds[4] + reds[5]) + (reds[6] + reds[7]));

    const float inv = 1.f / s;
    a.x = e0 * inv; a.y = e1 * inv; a.z = e2 * inv; a.w = e3 * inv;
    r4[tid] = a;
}

extern "C" void kernel_launch(void* const* d_in, const int* in_sizes, int n_in,
                              void* d_out, int out_size, void* d_ws, size_t ws_size,
                              hipStream_t stream) {
    const float* hidden = (const float*)d_in[0];  // [B, H]
    const float* enc    = (const float*)d_in[1];  // [L, B, H]
    const float* W      = (const float*)d_in[2];  // [H, H]
    // d_in[3] (bias) cancels in the softmax over l — provably irrelevant.

    float* partial = (float*)d_ws;                        // [B, GC, H]  2 MB
    float* out     = (float*)d_out;                       // [B, 1, L]   fp32

    // 1) partial = split-K hidden @ W (GC=8 chunks; summed in scores prologue)
    u_partial_kernel<<<dim3(GC, HC, BG), 256, 0, stream>>>(hidden, W, partial);

    // 2) scores[b,l] = dot(enc[l,b,:], sum_gc partial[b][gc][:]) -> d_out
    scores_kernel<<<(B * L / ITER) / 4, 256, 0, stream>>>(
        (const f32x4*)enc, (const f32x4*)partial, out);

    // 3) softmax over l, in place
    softmax_kernel<<<B, 512, 0, stream>>>(out);
}